// Round 6
// baseline (95.525 us; speedup 1.0000x reference)
//
#include <hip/hip_runtime.h>

#define Bc    16
#define Vc    20
#define MFc   32
#define MTc   8
#define NPc   4
#define Kc    3
#define Rc    12
#define Dc    128
#define NOUTc 64

#define TOTAL_UNITS (Bc * Vc * MTc * MFc)   // 81920 ; unit u = bv*256 + f*8 + t
#define XPU (NPc * Kc * Rc)                 // 144 floats of rel per unit
#define NBLOCKS 2048                        // 8 blocks/CU exactly, uniform work
#define UNITS_PER_BLOCK (TOTAL_UNITS / NBLOCKS)  // 40
#define NGROUPS (UNITS_PER_BLOCK / 4)            // 10 (keep EVEN: tail uses po[1])

// Setup: extract W_rel diagonals into contiguous diagT[d][r].
__global__ void diag_extract(const float* __restrict__ W_rel,
                             float* __restrict__ diagT) {
    const int i = blockIdx.x * 256 + threadIdx.x;  // over R*D = 1536
    if (i < Rc * Dc) {
        const int d = i / Rc, r = i % Rc;
        diagT[i] = W_rel[r * Dc * Dc + d * (Dc + 1)];
    }
}

__global__ __launch_bounds__(256)
void gal_kernel(const float* __restrict__ src,    // [B,V,MT,MF,D]
                const float* __restrict__ rel,    // [B,V,MF,MT,NP,K,R] = [u][144]
                const float* __restrict__ diagT,  // [D,R] contiguous
                const float* __restrict__ attn_w, // [NOUT+D]
                const float* __restrict__ out_w,  // [D,NOUT]
                const float* __restrict__ out_b,  // [NOUT]
                float* __restrict__ out)          // [B,V,NOUT]
{
    __shared__ float zs[2][4][Dc];        // 4 KB: double-buffered per-group z
    __shared__ float po[2][16][NOUTc];    // 8 KB: double-buffered GEMV partials

    const int tid  = threadIdx.x;
    const int lane = tid & 63;
    const int wv   = tid >> 6;

    const int u_base = blockIdx.x * UNITS_PER_BLOCK;
    const int bv0    = u_base >> 8;       // 256 units per bv

    // out_w rows [32*wv, 32*wv+32) in registers (lane = output column n)
    float Wreg[32];
#pragma unroll
    for (int j = 0; j < 32; ++j)
        Wreg[j] = out_w[(32 * wv + j) * NOUTc + lane];

    // W_rel diagonal caches (vectorized from contiguous diagT)
    float diag0[Rc], diag1[Rc];
    {
        const float4* dg0 = (const float4*)(diagT + lane * Rc);
        const float4* dg1 = (const float4*)(diagT + (lane + 64) * Rc);
#pragma unroll
        for (int q = 0; q < 3; ++q) {
            const float4 v0 = dg0[q], v1 = dg1[q];
            diag0[4 * q + 0] = v0.x; diag0[4 * q + 1] = v0.y;
            diag0[4 * q + 2] = v0.z; diag0[4 * q + 3] = v0.w;
            diag1[4 * q + 0] = v1.x; diag1[4 * q + 1] = v1.y;
            diag1[4 * q + 2] = v1.z; diag1[4 * q + 3] = v1.w;
        }
    }
    const float aw0 = attn_w[NOUTc + lane];
    const float aw1 = attn_w[NOUTc + lane + 64];
    const float ob  = out_b[lane];

    float acc0 = 0.f, acc1 = 0.f;   // per-bv accumulators (block spans <=1 boundary)

    for (int g = 0; g < NGROUPS; ++g) {
        const int X = g & 1, Y = X ^ 1;

        // ---- P1: this wave's unit -> z, write to zs[X] ----
        const int u   = u_base + g * 4 + wv;
        const int t   = u & (MTc - 1);
        const int f   = (u >> 3) & (MFc - 1);
        const int ubv = u >> 8;

        const int xoff = __builtin_amdgcn_readfirstlane(u * XPU);
        const float* __restrict__ x  = rel + xoff;   // wave-uniform -> s_load
        const float* __restrict__ sp = src + ((ubv * MTc + t) * MFc + f) * Dc;
        const float s0 = sp[lane];
        const float s1 = sp[lane + 64];
        const float c0 = s0 * aw0;   // defer-s: logits use c = s*aw
        const float c1 = s1 * aw1;

        float wq0[NPc], wq1[NPc], lg[NPc];
        // k-outer / p-pair-inner: 6 load-wait segments of 48 FMA each
#pragma unroll
        for (int pp = 0; pp < 2; ++pp) {
            float wa0 = 1.f, wa1 = 1.f, wb0 = 1.f, wb1 = 1.f;
#pragma unroll 1
            for (int k = 0; k < Kc; ++k) {
                const float* __restrict__ xk = x + pp * 2 * Kc * Rc + k * Rc;
                float aa0 = 0.f, aa1 = 0.f, ab0 = 0.f, ab1 = 0.f;
#pragma unroll
                for (int r = 0; r < Rc; ++r) {
                    const float xa = xk[r];            // path 2*pp   (s_load)
                    const float xb = xk[Kc * Rc + r];  // path 2*pp+1 (s_load)
                    aa0 = fmaf(xa, diag0[r], aa0);
                    aa1 = fmaf(xa, diag1[r], aa1);
                    ab0 = fmaf(xb, diag0[r], ab0);
                    ab1 = fmaf(xb, diag1[r], ab1);
                }
                wa0 *= aa0; wa1 *= aa1; wb0 *= ab0; wb1 *= ab1;
            }
            wq0[2 * pp]     = wa0; wq1[2 * pp]     = wa1;
            wq0[2 * pp + 1] = wb0; wq1[2 * pp + 1] = wb1;
            lg[2 * pp]      = fmaf(wa0, c0, wa1 * c1);
            lg[2 * pp + 1]  = fmaf(wb0, c0, wb1 * c1);
        }

        // butterfly-reduce the 4 logits across the wave
#pragma unroll
        for (int off = 32; off > 0; off >>= 1) {
#pragma unroll
            for (int p = 0; p < NPc; ++p) lg[p] += __shfl_xor(lg[p], off, 64);
        }

        // softmax over NP=4 (uniform s-dot + bias cancel exactly)
        const float m  = fmaxf(fmaxf(lg[0], lg[1]), fmaxf(lg[2], lg[3]));
        const float e0 = __expf(lg[0] - m), e1 = __expf(lg[1] - m);
        const float e2 = __expf(lg[2] - m), e3 = __expf(lg[3] - m);
        const float inv = 1.f / (e0 + e1 + e2 + e3);
        const float a0 = e0 * inv, a1 = e1 * inv, a2 = e2 * inv, a3 = e3 * inv;

        // z = s * sum_p a_p * w_p   (defer-s)
        zs[X][wv][lane] =
            s0 * (((a0 * wq0[0] + a1 * wq0[1]) + (a2 * wq0[2] + a3 * wq0[3])));
        zs[X][wv][lane + 64] =
            s1 * (((a0 * wq1[0] + a1 * wq1[1]) + (a2 * wq1[2] + a3 * wq1[3])));

        __syncthreads();   // zs[X] ready; po[X] free

        // ---- P2(g): 32-row GEMV slice for all 4 units vs register W ----
#pragma unroll
        for (int uu = 0; uu < 4; ++uu) {
            const float4* zq = (const float4*)&zs[X][uu][32 * wv];  // broadcast
            float p0 = 0.f, p1 = 0.f, p2 = 0.f, p3 = 0.f;
#pragma unroll
            for (int q = 0; q < 8; ++q) {
                const float4 z4 = zq[q];
                p0 = fmaf(z4.x, Wreg[4 * q + 0], p0);
                p1 = fmaf(z4.y, Wreg[4 * q + 1], p1);
                p2 = fmaf(z4.z, Wreg[4 * q + 2], p2);
                p3 = fmaf(z4.w, Wreg[4 * q + 3], p3);
            }
            po[X][uu * 4 + wv][lane] = (p0 + p1) + (p2 + p3);
        }

        // ---- P3(g-1): finish previous group's unit slot wv (no barrier) ----
        if (g > 0) {
            const int up = u_base + (g - 1) * 4 + wv;
            const float v = po[Y][wv * 4 + 0][lane] + po[Y][wv * 4 + 1][lane]
                          + po[Y][wv * 4 + 2][lane] + po[Y][wv * 4 + 3][lane];
            const float rv = fmaxf(ob + v, 0.f);
            if ((up >> 8) == bv0) acc0 += rv; else acc1 += rv;
        }
    }

    // ---- final P3 for the last group (NGROUPS even -> reads po[1]) ----
    __syncthreads();
    {
        const int XL = (NGROUPS - 1) & 1;
        const int up = u_base + (NGROUPS - 1) * 4 + wv;
        const float v = po[XL][wv * 4 + 0][lane] + po[XL][wv * 4 + 1][lane]
                      + po[XL][wv * 4 + 2][lane] + po[XL][wv * 4 + 3][lane];
        const float rv = fmaxf(ob + v, 0.f);
        if ((up >> 8) == bv0) acc0 += rv; else acc1 += rv;
    }

    // block reduction: 4 waves -> <=2 atomics per block (po[0] disjoint from po[1])
    po[0][wv][lane]     = acc0;
    po[0][8 + wv][lane] = acc1;
    __syncthreads();
    if (wv == 0) {
        const float t0 = po[0][0][lane] + po[0][1][lane]
                       + po[0][2][lane] + po[0][3][lane];
        atomicAdd(&out[bv0 * NOUTc + lane], t0);
        const int bvLast = (u_base + UNITS_PER_BLOCK - 1) >> 8;
        if (bvLast != bv0) {
            const float t1 = po[0][8][lane] + po[0][9][lane]
                           + po[0][10][lane] + po[0][11][lane];
            atomicAdd(&out[(bv0 + 1) * NOUTc + lane], t1);
        }
    }
}

extern "C" void kernel_launch(void* const* d_in, const int* in_sizes, int n_in,
                              void* d_out, int out_size, void* d_ws, size_t ws_size,
                              hipStream_t stream) {
    const float* src    = (const float*)d_in[0];  // source_embed
    const float* rel    = (const float*)d_in[1];  // rel_index
    // d_in[2] = s        (cancels in softmax)
    const float* W_rel  = (const float*)d_in[3];
    const float* attn_w = (const float*)d_in[4];
    // d_in[5] = attn_b   (cancels in softmax)
    const float* out_w  = (const float*)d_in[6];
    const float* out_b  = (const float*)d_in[7];
    float* out   = (float*)d_out;
    float* diagT = (float*)d_ws;                  // R*D floats = 6 KB

    hipMemsetAsync(out, 0, (size_t)out_size * sizeof(float), stream);
    diag_extract<<<(Rc * Dc + 255) / 256, 256, 0, stream>>>(W_rel, diagT);
    gal_kernel<<<NBLOCKS, 256, 0, stream>>>(src, rel, diagT, attn_w, out_w, out_b, out);
}

// Round 7
// 88.820 us; speedup vs baseline: 1.0755x; 1.0755x over previous
//
#include <hip/hip_runtime.h>

#define Bc    16
#define Vc    20
#define MFc   32
#define MTc   8
#define NPc   4
#define Kc    3
#define Rc    12
#define Dc    128
#define NOUTc 64

#define TOTAL_UNITS (Bc * Vc * MTc * MFc)   // 81920 ; unit u = bv*256 + f*8 + t
#define XPU (NPc * Kc * Rc)                 // 144 floats of rel per unit
#define NBLOCKS 2048                        // 8 blocks/CU exactly, uniform work
#define UNITS_PER_BLOCK (TOTAL_UNITS / NBLOCKS)  // 40
#define NGROUPS (UNITS_PER_BLOCK / 4)            // 10 (keep EVEN: tail uses po[1])

// Setup: extract W_rel diagonals into contiguous diagT[d][r].
__global__ void diag_extract(const float* __restrict__ W_rel,
                             float* __restrict__ diagT) {
    const int i = blockIdx.x * 256 + threadIdx.x;  // over R*D = 1536
    if (i < Rc * Dc) {
        const int d = i / Rc, r = i % Rc;
        diagT[i] = W_rel[r * Dc * Dc + d * (Dc + 1)];
    }
}

__global__ __launch_bounds__(256)
void gal_kernel(const float* __restrict__ src,    // [B,V,MT,MF,D]
                const float* __restrict__ rel,    // [B,V,MF,MT,NP,K,R] = [u][144]
                const float* __restrict__ diagT,  // [D,R] contiguous
                const float* __restrict__ attn_w, // [NOUT+D]
                const float* __restrict__ out_w,  // [D,NOUT]
                const float* __restrict__ out_b,  // [NOUT]
                float* __restrict__ out)          // [B,V,NOUT]
{
    __shared__ float zs[2][4][Dc];        // 4 KB: double-buffered per-group z
    __shared__ float po[2][16][NOUTc];    // 8 KB: double-buffered GEMV partials

    const int tid  = threadIdx.x;
    const int lane = tid & 63;
    const int wv   = tid >> 6;

    const int u_base = blockIdx.x * UNITS_PER_BLOCK;
    const int bv0    = u_base >> 8;       // 256 units per bv

    // out_w rows [32*wv, 32*wv+32) in registers (lane = output column n)
    float Wreg[32];
#pragma unroll
    for (int j = 0; j < 32; ++j)
        Wreg[j] = out_w[(32 * wv + j) * NOUTc + lane];

    // W_rel diagonal caches (vectorized from contiguous diagT)
    float diag0[Rc], diag1[Rc];
    {
        const float4* dg0 = (const float4*)(diagT + lane * Rc);
        const float4* dg1 = (const float4*)(diagT + (lane + 64) * Rc);
#pragma unroll
        for (int q = 0; q < 3; ++q) {
            const float4 v0 = dg0[q], v1 = dg1[q];
            diag0[4 * q + 0] = v0.x; diag0[4 * q + 1] = v0.y;
            diag0[4 * q + 2] = v0.z; diag0[4 * q + 3] = v0.w;
            diag1[4 * q + 0] = v1.x; diag1[4 * q + 1] = v1.y;
            diag1[4 * q + 2] = v1.z; diag1[4 * q + 3] = v1.w;
        }
    }
    // fold log2(e) into the attn weights: logits move to log2 domain,
    // softmax then uses exp2f (v_exp_f32 is natively 2^x). Softmax invariant.
    const float LOG2E = 1.4426950408889634f;
    const float aw0 = attn_w[NOUTc + lane] * LOG2E;
    const float aw1 = attn_w[NOUTc + lane + 64] * LOG2E;
    const float ob  = out_b[lane];

    float acc0 = 0.f, acc1 = 0.f;   // per-bv accumulators (block spans <=1 boundary)

    for (int g = 0; g < NGROUPS; ++g) {
        const int X = g & 1, Y = X ^ 1;

        // ---- L2-warming prefetch of NEXT group's rel chunk (2304 B contig) ----
        float4 pfr = make_float4(0.f, 0.f, 0.f, 0.f);
        if (tid < 144) {
            int off = (u_base + (g + 1) * 4) * XPU + tid * 4;
            const int maxoff = TOTAL_UNITS * XPU - 4 * 144;
            if (off > maxoff) off = maxoff;
            pfr = *(const float4*)(rel + off);
        }

        // ---- P1: this wave's unit -> z, write to zs[X] ----
        const int u   = u_base + g * 4 + wv;
        const int t   = u & (MTc - 1);
        const int f   = (u >> 3) & (MFc - 1);
        const int ubv = u >> 8;

        const int xoff = __builtin_amdgcn_readfirstlane(u * XPU);
        const float* __restrict__ x  = rel + xoff;   // wave-uniform -> s_load
        const float* __restrict__ sp = src + ((ubv * MTc + t) * MFc + f) * Dc;
        const float s0 = sp[lane];
        const float s1 = sp[lane + 64];

        // ---- line-touch prefetch of NEXT unit's src row (512 B, 8 lines) ----
        float4 pfs = make_float4(0.f, 0.f, 0.f, 0.f);
        {
            int un = u + 4;
            if (un > TOTAL_UNITS - 1) un = TOTAL_UNITS - 1;
            const int tn = un & (MTc - 1), fn = (un >> 3) & (MFc - 1);
            const float* spn = src + (((un >> 8) * MTc + tn) * MFc + fn) * Dc;
            if (lane < 32) pfs = *(const float4*)(spn + lane * 4);
        }

        const float c0 = s0 * aw0;   // defer-s: logits use c = s*aw (log2 domain)
        const float c1 = s1 * aw1;

        float wq0[NPc], wq1[NPc], lg[NPc];
        // k-outer / p-pair-inner: 6 load-wait segments of 48 FMA each
#pragma unroll
        for (int pp = 0; pp < 2; ++pp) {
            float wa0 = 1.f, wa1 = 1.f, wb0 = 1.f, wb1 = 1.f;
#pragma unroll 1
            for (int k = 0; k < Kc; ++k) {
                const float* __restrict__ xk = x + pp * 2 * Kc * Rc + k * Rc;
                float aa0 = 0.f, aa1 = 0.f, ab0 = 0.f, ab1 = 0.f;
#pragma unroll
                for (int r = 0; r < Rc; ++r) {
                    const float xa = xk[r];            // path 2*pp   (s_load)
                    const float xb = xk[Kc * Rc + r];  // path 2*pp+1 (s_load)
                    aa0 = fmaf(xa, diag0[r], aa0);
                    aa1 = fmaf(xa, diag1[r], aa1);
                    ab0 = fmaf(xb, diag0[r], ab0);
                    ab1 = fmaf(xb, diag1[r], ab1);
                }
                wa0 *= aa0; wa1 *= aa1; wb0 *= ab0; wb1 *= ab1;
            }
            wq0[2 * pp]     = wa0; wq1[2 * pp]     = wa1;
            wq0[2 * pp + 1] = wb0; wq1[2 * pp + 1] = wb1;
            lg[2 * pp]      = fmaf(wa0, c0, wa1 * c1);
            lg[2 * pp + 1]  = fmaf(wb0, c0, wb1 * c1);
        }

        // butterfly-reduce the 4 logits across the wave
#pragma unroll
        for (int off = 32; off > 0; off >>= 1) {
#pragma unroll
            for (int p = 0; p < NPc; ++p) lg[p] += __shfl_xor(lg[p], off, 64);
        }

        // softmax over NP=4 in log2 domain (uniform s-dot + bias cancel exactly)
        const float m  = fmaxf(fmaxf(lg[0], lg[1]), fmaxf(lg[2], lg[3]));
        const float e0 = exp2f(lg[0] - m), e1 = exp2f(lg[1] - m);
        const float e2 = exp2f(lg[2] - m), e3 = exp2f(lg[3] - m);
        const float inv = 1.f / (e0 + e1 + e2 + e3);
        const float a0 = e0 * inv, a1 = e1 * inv, a2 = e2 * inv, a3 = e3 * inv;

        // z = s * sum_p a_p * w_p   (defer-s)
        zs[X][wv][lane] =
            s0 * (((a0 * wq0[0] + a1 * wq0[1]) + (a2 * wq0[2] + a3 * wq0[3])));
        zs[X][wv][lane + 64] =
            s1 * (((a0 * wq1[0] + a1 * wq1[1]) + (a2 * wq1[2] + a3 * wq1[3])));

        __syncthreads();   // zs[X] ready; po[X] free

        // ---- P2(g): 32-row GEMV slice for all 4 units vs register W ----
#pragma unroll
        for (int uu = 0; uu < 4; ++uu) {
            const float4* zq = (const float4*)&zs[X][uu][32 * wv];  // broadcast
            float p0 = 0.f, p1 = 0.f, p2 = 0.f, p3 = 0.f;
#pragma unroll
            for (int q = 0; q < 8; ++q) {
                const float4 z4 = zq[q];
                p0 = fmaf(z4.x, Wreg[4 * q + 0], p0);
                p1 = fmaf(z4.y, Wreg[4 * q + 1], p1);
                p2 = fmaf(z4.z, Wreg[4 * q + 2], p2);
                p3 = fmaf(z4.w, Wreg[4 * q + 3], p3);
            }
            po[X][uu * 4 + wv][lane] = (p0 + p1) + (p2 + p3);
        }

        // ---- P3(g-1): finish previous group's unit slot wv (no barrier) ----
        if (g > 0) {
            const int up = u_base + (g - 1) * 4 + wv;
            const float v = po[Y][wv * 4 + 0][lane] + po[Y][wv * 4 + 1][lane]
                          + po[Y][wv * 4 + 2][lane] + po[Y][wv * 4 + 3][lane];
            const float rv = fmaxf(ob + v, 0.f);
            if ((up >> 8) == bv0) acc0 += rv; else acc1 += rv;
        }

        // consume prefetches late: waitcnt lands after a full group of compute
        asm volatile("" :: "v"(pfr.x), "v"(pfr.y), "v"(pfr.z), "v"(pfr.w),
                           "v"(pfs.x), "v"(pfs.y), "v"(pfs.z), "v"(pfs.w));
    }

    // ---- final P3 for the last group (NGROUPS even -> reads po[1]) ----
    __syncthreads();
    {
        const int XL = (NGROUPS - 1) & 1;
        const int up = u_base + (NGROUPS - 1) * 4 + wv;
        const float v = po[XL][wv * 4 + 0][lane] + po[XL][wv * 4 + 1][lane]
                      + po[XL][wv * 4 + 2][lane] + po[XL][wv * 4 + 3][lane];
        const float rv = fmaxf(ob + v, 0.f);
        if ((up >> 8) == bv0) acc0 += rv; else acc1 += rv;
    }

    // block reduction: 4 waves -> <=2 atomics per block (po[0] disjoint from po[1])
    po[0][wv][lane]     = acc0;
    po[0][8 + wv][lane] = acc1;
    __syncthreads();
    if (wv == 0) {
        const float t0 = po[0][0][lane] + po[0][1][lane]
                       + po[0][2][lane] + po[0][3][lane];
        atomicAdd(&out[bv0 * NOUTc + lane], t0);
        const int bvLast = (u_base + UNITS_PER_BLOCK - 1) >> 8;
        if (bvLast != bv0) {
            const float t1 = po[0][8][lane] + po[0][9][lane]
                           + po[0][10][lane] + po[0][11][lane];
            atomicAdd(&out[(bv0 + 1) * NOUTc + lane], t1);
        }
    }
}

extern "C" void kernel_launch(void* const* d_in, const int* in_sizes, int n_in,
                              void* d_out, int out_size, void* d_ws, size_t ws_size,
                              hipStream_t stream) {
    const float* src    = (const float*)d_in[0];  // source_embed
    const float* rel    = (const float*)d_in[1];  // rel_index
    // d_in[2] = s        (cancels in softmax)
    const float* W_rel  = (const float*)d_in[3];
    const float* attn_w = (const float*)d_in[4];
    // d_in[5] = attn_b   (cancels in softmax)
    const float* out_w  = (const float*)d_in[6];
    const float* out_b  = (const float*)d_in[7];
    float* out   = (float*)d_out;
    float* diagT = (float*)d_ws;                  // R*D floats = 6 KB

    hipMemsetAsync(out, 0, (size_t)out_size * sizeof(float), stream);
    diag_extract<<<(Rc * Dc + 255) / 256, 256, 0, stream>>>(W_rel, diagT);
    gal_kernel<<<NBLOCKS, 256, 0, stream>>>(src, rel, diagT, attn_w, out_w, out_b, out);
}

// Round 8
// 85.502 us; speedup vs baseline: 1.1172x; 1.0388x over previous
//
#include <hip/hip_runtime.h>

typedef float f32x2 __attribute__((ext_vector_type(2)));

#define Bc    16
#define Vc    20
#define MFc   32
#define MTc   8
#define NPc   4
#define Kc    3
#define Rc    12
#define Dc    128
#define NOUTc 64

#define TOTAL_UNITS (Bc * Vc * MTc * MFc)   // 81920 ; unit u = bv*256 + f*8 + t
#define XPU (NPc * Kc * Rc)                 // 144 floats of rel per unit
#define NBLOCKS 2048                        // 8 blocks/CU exactly, uniform work
#define UNITS_PER_BLOCK (TOTAL_UNITS / NBLOCKS)  // 40
#define NGROUPS (UNITS_PER_BLOCK / 4)            // 10 (keep EVEN: tail uses po[1])

// Setup: extract W_rel diagonals into r-major diagR[r][d] (lane's d-pair is
// 8B contiguous -> float2 loads).
__global__ void diag_extract(const float* __restrict__ W_rel,
                             float* __restrict__ diagR) {
    const int i = blockIdx.x * 256 + threadIdx.x;  // over R*D = 1536
    if (i < Rc * Dc) {
        const int r = i / Dc, d = i % Dc;
        diagR[i] = W_rel[(r * Dc + d) * Dc + d];
    }
}

__global__ __launch_bounds__(256)
void gal_kernel(const float* __restrict__ src,    // [B,V,MT,MF,D]
                const float* __restrict__ rel,    // [B,V,MF,MT,NP,K,R] = [u][144]
                const float* __restrict__ diagR,  // [R][D] r-major
                const float* __restrict__ attn_w, // [NOUT+D]
                const float* __restrict__ out_w,  // [D,NOUT]
                const float* __restrict__ out_b,  // [NOUT]
                float* __restrict__ out)          // [B,V,NOUT]
{
    __shared__ float zs[2][4][Dc];        // 4 KB: double-buffered per-group z
    __shared__ float po[2][16][NOUTc];    // 8 KB: double-buffered GEMV partials

    const int tid  = threadIdx.x;
    const int lane = tid & 63;
    const int wv   = tid >> 6;

    const int u_base = blockIdx.x * UNITS_PER_BLOCK;
    const int bv0    = u_base >> 8;       // 256 units per bv

    // out_w rows [32*wv, 32*wv+32) in registers (lane = output column n)
    float Wreg[32];
#pragma unroll
    for (int j = 0; j < 32; ++j)
        Wreg[j] = out_w[(32 * wv + j) * NOUTc + lane];

    // W_rel diagonal pairs for this lane's d = {2*lane, 2*lane+1}
    f32x2 dg[Rc];
#pragma unroll
    for (int r = 0; r < Rc; ++r)
        dg[r] = *(const f32x2*)(diagR + r * Dc + 2 * lane);

    // fold log2(e) into attn weights: softmax via exp2 (v_exp_f32 is 2^x)
    const float LOG2E = 1.4426950408889634f;
    const f32x2 aw2 = *(const f32x2*)(attn_w + NOUTc + 2 * lane) * LOG2E;
    const float ob  = out_b[lane];

    float acc0 = 0.f, acc1 = 0.f;   // per-bv accumulators (block spans <=1 boundary)

    for (int g = 0; g < NGROUPS; ++g) {
        const int X = g & 1, Y = X ^ 1;

        // ---- L2-warming prefetch of NEXT group's rel chunk (2304 B contig) ----
        float4 pfr = make_float4(0.f, 0.f, 0.f, 0.f);
        if (tid < 144) {
            int off = (u_base + (g + 1) * 4) * XPU + tid * 4;
            const int maxoff = TOTAL_UNITS * XPU - 4 * 144;
            if (off > maxoff) off = maxoff;
            pfr = *(const float4*)(rel + off);
        }

        // ---- P1: this wave's unit -> z, write to zs[X] ----
        const int u   = u_base + g * 4 + wv;
        const int t   = u & (MTc - 1);
        const int f   = (u >> 3) & (MFc - 1);
        const int ubv = u >> 8;

        const int xoff = __builtin_amdgcn_readfirstlane(u * XPU);
        const float* __restrict__ x  = rel + xoff;   // wave-uniform -> s_load
        const float* __restrict__ sp = src + ((ubv * MTc + t) * MFc + f) * Dc;
        const f32x2 s2 = *(const f32x2*)(sp + 2 * lane);

        // ---- line-touch prefetch of NEXT unit's src row (512 B, 8 lines) ----
        float4 pfs = make_float4(0.f, 0.f, 0.f, 0.f);
        {
            int un = u + 4;
            if (un > TOTAL_UNITS - 1) un = TOTAL_UNITS - 1;
            const int tn = un & (MTc - 1), fn = (un >> 3) & (MFc - 1);
            const float* spn = src + (((un >> 8) * MTc + tn) * MFc + fn) * Dc;
            if (lane < 32) pfs = *(const float4*)(spn + lane * 4);
        }

        const f32x2 c2 = s2 * aw2;   // defer-s: logit = dot(w_p, c2) (log2 dom.)

        // k-outer, all 4 paths inner: 3 load-wait segments, 44 pk_fma each.
        // r=0 exploits W_rel[0] == all-ones (diag[0]=1): acc starts at x value.
        f32x2 w0v = {1.f, 1.f}, w1v = {1.f, 1.f}, w2v = {1.f, 1.f}, w3v = {1.f, 1.f};
#pragma unroll 1
        for (int k = 0; k < Kc; ++k) {
            const float* __restrict__ xk = x + k * Rc;
            const float x00 = xk[0], x10 = xk[36], x20 = xk[72], x30 = xk[108];
            f32x2 a0 = {x00, x00};
            f32x2 a1 = {x10, x10};
            f32x2 a2 = {x20, x20};
            f32x2 a3 = {x30, x30};
#pragma unroll
            for (int r = 1; r < Rc; ++r) {
                const float x0 = xk[r], x1 = xk[36 + r];
                const float x2 = xk[72 + r], x3 = xk[108 + r];
                a0 = __builtin_elementwise_fma((f32x2){x0, x0}, dg[r], a0);
                a1 = __builtin_elementwise_fma((f32x2){x1, x1}, dg[r], a1);
                a2 = __builtin_elementwise_fma((f32x2){x2, x2}, dg[r], a2);
                a3 = __builtin_elementwise_fma((f32x2){x3, x3}, dg[r], a3);
            }
            w0v *= a0; w1v *= a1; w2v *= a2; w3v *= a3;
        }

        float lg[NPc];
        {
            const f32x2 t0 = w0v * c2, t1 = w1v * c2;
            const f32x2 t2 = w2v * c2, t3 = w3v * c2;
            lg[0] = t0.x + t0.y; lg[1] = t1.x + t1.y;
            lg[2] = t2.x + t2.y; lg[3] = t3.x + t3.y;
        }

        // butterfly-reduce the 4 logits across the wave
#pragma unroll
        for (int off = 32; off > 0; off >>= 1) {
#pragma unroll
            for (int p = 0; p < NPc; ++p) lg[p] += __shfl_xor(lg[p], off, 64);
        }

        // softmax over NP=4 in log2 domain (uniform s-dot + bias cancel exactly)
        const float m  = fmaxf(fmaxf(lg[0], lg[1]), fmaxf(lg[2], lg[3]));
        const float e0 = exp2f(lg[0] - m), e1 = exp2f(lg[1] - m);
        const float e2 = exp2f(lg[2] - m), e3 = exp2f(lg[3] - m);
        const float inv = 1.f / (e0 + e1 + e2 + e3);
        const float a0s = e0 * inv, a1s = e1 * inv, a2s = e2 * inv, a3s = e3 * inv;

        // z = s * sum_p a_p * w_p   (packed)
        f32x2 zacc = w0v * (f32x2){a0s, a0s};
        zacc = __builtin_elementwise_fma(w1v, (f32x2){a1s, a1s}, zacc);
        zacc = __builtin_elementwise_fma(w2v, (f32x2){a2s, a2s}, zacc);
        zacc = __builtin_elementwise_fma(w3v, (f32x2){a3s, a3s}, zacc);
        *(f32x2*)(&zs[X][wv][2 * lane]) = s2 * zacc;

        __syncthreads();   // zs[X] ready; po[X] free

        // ---- P2(g): 32-row GEMV slice for all 4 units vs register W ----
#pragma unroll
        for (int uu = 0; uu < 4; ++uu) {
            const float4* zq = (const float4*)&zs[X][uu][32 * wv];  // broadcast
            float p0 = 0.f, p1 = 0.f, p2 = 0.f, p3 = 0.f;
#pragma unroll
            for (int q = 0; q < 8; ++q) {
                const float4 z4 = zq[q];
                p0 = fmaf(z4.x, Wreg[4 * q + 0], p0);
                p1 = fmaf(z4.y, Wreg[4 * q + 1], p1);
                p2 = fmaf(z4.z, Wreg[4 * q + 2], p2);
                p3 = fmaf(z4.w, Wreg[4 * q + 3], p3);
            }
            po[X][uu * 4 + wv][lane] = (p0 + p1) + (p2 + p3);
        }

        // ---- P3(g-1): finish previous group's unit slot wv (no barrier) ----
        if (g > 0) {
            const int up = u_base + (g - 1) * 4 + wv;
            const float v = po[Y][wv * 4 + 0][lane] + po[Y][wv * 4 + 1][lane]
                          + po[Y][wv * 4 + 2][lane] + po[Y][wv * 4 + 3][lane];
            const float rv = fmaxf(ob + v, 0.f);
            if ((up >> 8) == bv0) acc0 += rv; else acc1 += rv;
        }

        // consume prefetches late: waitcnt lands after a full group of compute
        asm volatile("" :: "v"(pfr.x), "v"(pfr.y), "v"(pfr.z), "v"(pfr.w),
                           "v"(pfs.x), "v"(pfs.y), "v"(pfs.z), "v"(pfs.w));
    }

    // ---- final P3 for the last group (NGROUPS even -> reads po[1]) ----
    __syncthreads();
    {
        const int XL = (NGROUPS - 1) & 1;
        const int up = u_base + (NGROUPS - 1) * 4 + wv;
        const float v = po[XL][wv * 4 + 0][lane] + po[XL][wv * 4 + 1][lane]
                      + po[XL][wv * 4 + 2][lane] + po[XL][wv * 4 + 3][lane];
        const float rv = fmaxf(ob + v, 0.f);
        if ((up >> 8) == bv0) acc0 += rv; else acc1 += rv;
    }

    // block reduction: 4 waves -> <=2 atomics per block (po[0] disjoint from po[1])
    po[0][wv][lane]     = acc0;
    po[0][8 + wv][lane] = acc1;
    __syncthreads();
    if (wv == 0) {
        const float t0 = po[0][0][lane] + po[0][1][lane]
                       + po[0][2][lane] + po[0][3][lane];
        atomicAdd(&out[bv0 * NOUTc + lane], t0);
        const int bvLast = (u_base + UNITS_PER_BLOCK - 1) >> 8;
        if (bvLast != bv0) {
            const float t1 = po[0][8][lane] + po[0][9][lane]
                           + po[0][10][lane] + po[0][11][lane];
            atomicAdd(&out[(bv0 + 1) * NOUTc + lane], t1);
        }
    }
}

extern "C" void kernel_launch(void* const* d_in, const int* in_sizes, int n_in,
                              void* d_out, int out_size, void* d_ws, size_t ws_size,
                              hipStream_t stream) {
    const float* src    = (const float*)d_in[0];  // source_embed
    const float* rel    = (const float*)d_in[1];  // rel_index
    // d_in[2] = s        (cancels in softmax)
    const float* W_rel  = (const float*)d_in[3];
    const float* attn_w = (const float*)d_in[4];
    // d_in[5] = attn_b   (cancels in softmax)
    const float* out_w  = (const float*)d_in[6];
    const float* out_b  = (const float*)d_in[7];
    float* out   = (float*)d_out;
    float* diagR = (float*)d_ws;                  // R*D floats = 6 KB

    hipMemsetAsync(out, 0, (size_t)out_size * sizeof(float), stream);
    diag_extract<<<(Rc * Dc + 255) / 256, 256, 0, stream>>>(W_rel, diagR);
    gal_kernel<<<NBLOCKS, 256, 0, stream>>>(src, rel, diagR, attn_w, out_w, out_b, out);
}

// Round 9
// 48.143 us; speedup vs baseline: 1.9842x; 1.7760x over previous
//
#include <hip/hip_runtime.h>
#include <hip/hip_bf16.h>

typedef short bf16x8 __attribute__((ext_vector_type(8)));
typedef float f32x4  __attribute__((ext_vector_type(4)));
typedef unsigned short u16;

#define Bc    16
#define Vc    20
#define MFc   32
#define MTc   8
#define NPc   4
#define Kc    3
#define Rc    12
#define Dc    128
#define NOUTc 64

#define TOTAL_UNITS (Bc * Vc * MTc * MFc)   // 81920 ; u = bv*256 + f*8 + t
#define XPU 144                             // rel floats per unit
#define NBLOCKS 1024                        // 4 blocks/CU
#define UPB 80                              // units per block
#define NBATCH 5                            // 16-unit batches per block

// d_ws tables (bf16 bits):
//   diagB[128 d][32 r]  @ 0     : W_rel diagonal, r>=12 zeroed (B-operand pad)
//   Wb   [64 n][128 d]  @ 4096  : out_w transposed (P2 B-operand, k-major)
__global__ void setup_tabs(const float* __restrict__ W_rel,
                           const float* __restrict__ out_w,
                           u16* __restrict__ ws) {
    const int i = blockIdx.x * 256 + threadIdx.x;
    if (i < 128 * 32) {
        const int d = i >> 5, r = i & 31;
        const float v = (r < Rc) ? W_rel[(r * Dc + d) * Dc + d] : 0.f;
        union { __hip_bfloat16 h; u16 u; } cv; cv.h = __float2bfloat16(v);
        ws[i] = cv.u;
    } else if (i < 128 * 32 + 64 * 128) {
        const int j = i - 128 * 32;
        const int n = j >> 7, d = j & 127;
        union { __hip_bfloat16 h; u16 u; } cv;
        cv.h = __float2bfloat16(out_w[d * NOUTc + n]);
        ws[i] = cv.u;
    }
}

__global__ __launch_bounds__(256)
void gal_kernel(const float* __restrict__ src,    // [B,V,MT,MF,D]
                const float* __restrict__ rel,    // [u][144]
                const u16*   __restrict__ diagB,  // [128][32] bf16
                const u16*   __restrict__ Wb,     // [64][128] bf16
                const float* __restrict__ attn_w, // [NOUT+D]
                const float* __restrict__ out_b,  // [NOUT]
                float* __restrict__ out)          // [B,V,NOUT]
{
    // zp[buf][unit-in-batch][p*128 + d] bf16, row padded 512->520 (bank balance)
    __shared__ __align__(16) u16 zp[2][16][520];   // 33.3 KB

    const int tid  = threadIdx.x;
    const int lane = tid & 63;
    const int wv   = tid >> 6;
    const int c    = lane & 15;   // MFMA col / A-row index
    const int g    = lane >> 4;   // MFMA k-group / C row-group

    const int u_base = blockIdx.x * UPB;
    const int bv0    = u_base >> 8;

    // hoisted P2 B-frags: wave owns N-tile wv; lane col n = wv*16+c, k=g*8+j
    bf16x8 wbf[4];
#pragma unroll
    for (int ks = 0; ks < 4; ++ks)
        wbf[ks] = *(const bf16x8*)(Wb + (wv * 16 + c) * Dc + ks * 32 + g * 8);

    const float LOG2E = 1.4426950408889634f;
    float aw_r[8];
#pragma unroll
    for (int t = 0; t < 8; ++t)
        aw_r[t] = attn_w[NOUTc + t * 16 + c] * LOG2E;
    const float ob = out_b[wv * 16 + c];

    // P1 A-frag geometry: A-row = c -> (p = c>>2, k = c&3; k==3 is a pad row
    // duplicating k=2 -> its C rows are simply never used). k-slice by g.
    const int pA  = c >> 2, klA = c & 3;
    const int rr  = pA * 3 + (klA < 3 ? klA : 2);
    const int ao0 = rr * Rc + (g & 1) * 8;         // r base of this kg slice
    const int ao1 = (g == 0) ? (ao0 + 4) : ao0;    // hi 4 only valid for kg0
    const bool vlo = (g <= 1);                     // k+0..3 carries real r
    const bool vhi = (g == 0);                     // k+4..7 carries real r

    const f32x4 zero4 = {0.f, 0.f, 0.f, 0.f};
    float accA = 0.f, accB = 0.f;

    for (int b = 0; b < NBATCH; ++b) {
        const int X   = b & 1;
        const int ub0 = u_base + b * 16;

        // ---- P1: each wave computes 4 units -> zp rows wv*4+j ----
        for (int j = 0; j < 4; ++j) {
            const int u = ub0 + wv * 4 + j;
            const float* __restrict__ xu = rel + u * XPU;
            const float4 La = *(const float4*)(xu + ao0);
            const float4 Lb = *(const float4*)(xu + ao1);

            const int t8 = u & 7, f5 = (u >> 3) & 31, ubv = u >> 8;
            const float* __restrict__ sp = src + ((ubv * MTc + t8) * MFc + f5) * Dc;
            float sld[8];
#pragma unroll
            for (int t = 0; t < 8; ++t) sld[t] = sp[t * 16 + c];

            // A-fragment: fp32 -> bf16 pairs, zero the padded k-slots
            union { __hip_bfloat162 h; unsigned int q; } q0, q1, q2, q3;
            q0.h = __float22bfloat162_rn(make_float2(La.x, La.y));
            q1.h = __float22bfloat162_rn(make_float2(La.z, La.w));
            q2.h = __float22bfloat162_rn(make_float2(Lb.x, Lb.y));
            q3.h = __float22bfloat162_rn(make_float2(Lb.z, Lb.w));
            union { bf16x8 v; unsigned int q[4]; } af;
            af.q[0] = vlo ? q0.q : 0u;
            af.q[1] = vlo ? q1.q : 0u;
            af.q[2] = vhi ? q2.q : 0u;
            af.q[3] = vhi ? q3.q : 0u;

            // 8 MFMAs over d-tiles: C[pk, d]; lane holds p=g, k=reg_idx
            f32x4 pa[8];
#pragma unroll
            for (int t = 0; t < 8; ++t) {
                const bf16x8 bf = *(const bf16x8*)(diagB + (t * 16 + c) * 32 + g * 8);
                pa[t] = __builtin_amdgcn_mfma_f32_16x16x32_bf16(af.v, bf, zero4, 0, 0, 0);
            }

            // k-product (local: regs 0..2 of own p) + logit partial
            float w[8], lp = 0.f;
#pragma unroll
            for (int t = 0; t < 8; ++t) {
                w[t] = pa[t][0] * pa[t][1] * pa[t][2];
                lp = fmaf(w[t], sld[t] * aw_r[t], lp);
            }
            lp += __shfl_xor(lp, 1);
            lp += __shfl_xor(lp, 2);
            lp += __shfl_xor(lp, 4);
            lp += __shfl_xor(lp, 8);
            const float lA = lp;                    // logit of p = g
            const float lB = __shfl_xor(lp, 16);    // p = g^1
            const float lC = __shfl_xor(lp, 32);    // p = g^2
            const float lD = __shfl_xor(lB, 32);    // p = g^3

            // softmax over 4 paths, log2 domain (uniform terms cancel)
            const float m   = fmaxf(fmaxf(lA, lB), fmaxf(lC, lD));
            const float eS  = exp2f(lA - m);
            const float sum = eS + exp2f(lB - m) + exp2f(lC - m) + exp2f(lD - m);
            const float aS  = eS * __builtin_amdgcn_rcpf(sum);  // own path weight

            // zp[unit][p*128 + d] = bf16(a_p * w_p * s), p = g, d = t*16+c
            u16* zr = &zp[X][wv * 4 + j][g * 128 + c];
#pragma unroll
            for (int t = 0; t < 8; ++t) {
                union { __hip_bfloat16 h; u16 u; } cv;
                cv.h = __float2bfloat16(aS * sld[t] * w[t]);
                zr[t * 16] = cv.u;
            }
        }

        __syncthreads();   // zp[X] complete; zp[X^1] untouched by this batch

        // ---- P2: [16 units x 512] @ Wb -> C[units, n]; wave = N-tile wv ----
        f32x4 ca = zero4, cb = zero4;
#pragma unroll
        for (int p = 0; p < 2; ++p)
#pragma unroll
            for (int ks = 0; ks < 4; ++ks) {
                const bf16x8 az = *(const bf16x8*)(&zp[X][c][p * 128 + ks * 32 + g * 8]);
                ca = __builtin_amdgcn_mfma_f32_16x16x32_bf16(az, wbf[ks], ca, 0, 0, 0);
            }
#pragma unroll
        for (int p = 2; p < 4; ++p)
#pragma unroll
            for (int ks = 0; ks < 4; ++ks) {
                const bf16x8 az = *(const bf16x8*)(&zp[X][c][p * 128 + ks * 32 + g * 8]);
                cb = __builtin_amdgcn_mfma_f32_16x16x32_bf16(az, wbf[ks], cb, 0, 0, 0);
            }

        // epilogue: bias + relu per unit-row, sum my 4 rows
        float su = 0.f;
#pragma unroll
        for (int i = 0; i < 4; ++i)
            su += fmaxf(ca[i] + cb[i] + ob, 0.f);
        if ((ub0 >> 8) == bv0) accA += su; else accB += su;
    }

    // reduce over row-groups (g) and emit: wave owns distinct n-range
    accA += __shfl_xor(accA, 16); accA += __shfl_xor(accA, 32);
    accB += __shfl_xor(accB, 16); accB += __shfl_xor(accB, 32);
    if (lane < 16) {
        atomicAdd(&out[bv0 * NOUTc + wv * 16 + lane], accA);
        const int bvL = (u_base + UPB - 1) >> 8;
        if (bvL != bv0) atomicAdd(&out[bvL * NOUTc + wv * 16 + lane], accB);
    }
}

extern "C" void kernel_launch(void* const* d_in, const int* in_sizes, int n_in,
                              void* d_out, int out_size, void* d_ws, size_t ws_size,
                              hipStream_t stream) {
    const float* src    = (const float*)d_in[0];  // source_embed
    const float* rel    = (const float*)d_in[1];  // rel_index
    // d_in[2] = s        (cancels in softmax)
    const float* W_rel  = (const float*)d_in[3];
    const float* attn_w = (const float*)d_in[4];
    // d_in[5] = attn_b   (cancels in softmax)
    const float* out_w  = (const float*)d_in[6];
    const float* out_b  = (const float*)d_in[7];
    float* out  = (float*)d_out;
    u16*   tabs = (u16*)d_ws;                     // 24 KB of bf16 tables

    hipMemsetAsync(out, 0, (size_t)out_size * sizeof(float), stream);
    setup_tabs<<<48, 256, 0, stream>>>(W_rel, out_w, tabs);
    gal_kernel<<<NBLOCKS, 256, 0, stream>>>(src, rel, tabs, tabs + 128 * 32,
                                            attn_w, out_b, out);
}